// Round 13
// baseline (442.665 us; speedup 1.0000x reference)
//
#include <hip/hip_runtime.h>
#include <hip/hip_bf16.h>
#include <stdint.h>

// Problem constants (fixed by setup_inputs)
#define NTOK   8192
#define TOPK   2
#define NEXP   8
#define DIN    2048
#define DOUT   2048
#define NK     (NTOK*TOPK)

// GEMM tiling: 256(M) x 128(N) tile, BK=32, 8 waves as 4(M) x 2(N),
// wave tile 64x64 = 4x4 MFMA 16x16x32 bf16 frags.
// CONVERGED CONFIG (R0-R12 search):
// - SHAPE (R7): 32x32x16 frags -> 4-way LDS bank conflict; 16-row pattern = 0.
// - REGISTERS (R5/R9): 128-reg acc spills or halves occupancy; 64-reg acc +
//   4 waves/SIMD is the feasible optimum.
// - OCCUPANCY (R1/R2/R4): 1-block/CU lockstep caps at ~33% MfmaUtil; keep
//   2 blocks/CU.
// - SCHEDULE (R3): counted-vmcnt NBUF=3 ring, one barrier + one vmcnt(3)
//   per K-tile. Asymmetric deep-A ring (R12): null -> reverted.
// - XCD swizzle (R6/R8): FETCH 288 -> ~190 MB; kept.
#define BM 256
#define BN 128
#define BK 32
#define KTILES  (DIN/BK)           // 64
#define SLOT    24576              // per-K-tile LDS: A 16 KB + B 8 KB
#define NBUF    3                  // 72 KB ring, prefetch depth 2 tiles

typedef __bf16 bf16_8 __attribute__((ext_vector_type(8)));  // 4 VGPRs, MFMA A/B frag
typedef float  f32x4  __attribute__((ext_vector_type(4)));  // MFMA C/D frag

// global->LDS direct load, 16B per lane. LDS dest = wave-uniform base + lane*16.
__device__ __forceinline__ void gl2lds16(const void* g, void* l) {
  auto gp = reinterpret_cast<const __attribute__((address_space(1))) uint32_t*>(
      reinterpret_cast<uintptr_t>(g));
  auto lp = reinterpret_cast<__attribute__((address_space(3))) uint32_t*>(
      reinterpret_cast<uintptr_t>(l));
  __builtin_amdgcn_global_load_lds(gp, lp, 16, 0, 0);
}

// Fused fp32 -> bf16 (RNE) for W then X — DENSE pattern (R13 change).
// Old form: thread loaded src[2i], src[2i+1] -> 32B lane stride, 50%-density
// transactions. New: one float4 per thread (16B dense load), one uint2 out
// (8B dense store). Same output layout; branch is uniform per block
// (nW4 = 8388608 is a multiple of 256).
__global__ __launch_bounds__(256)
void cvt_all(const float4* __restrict__ w, uint2* __restrict__ wD,
             const float4* __restrict__ x, uint2* __restrict__ xD,
             int nW4) {
  int j = blockIdx.x * 256 + threadIdx.x;
  const float4* src;
  uint2* dst;
  int i;
  if (j < nW4) { src = w; dst = wD; i = j; }
  else         { src = x; dst = xD; i = j - nW4; }
  float4 a = src[i];
  union { __bf16 h[4]; uint2 u; } r;
  r.h[0] = (__bf16)a.x; r.h[1] = (__bf16)a.y;
  r.h[2] = (__bf16)a.z; r.h[3] = (__bf16)a.w;
  dst[i] = r.u;
}

// Grouped GEMM over expert-sorted flat rows — R3 schedule + shape (166-169 us
// / ~38% MfmaUtil / 0 LDS conflicts) + XCD-aware bijective block swizzle
// (FETCH 288 -> ~190 MB; same-mtg blocks share an L2). R10 verbatim.
//
// Per K-tile t (counted-vmcnt NBUF=3 ring):
//   stage(t+2) -> slot (t+2)%3   (3 gload_lds; WAR-safe: slot (t-1)%3's
//                                 reads were consumed before end-of-(t-1)
//                                 barrier, and this issue is after it)
//   ds_read af[0..3], bf[0..3] of tile t; 16 x MFMA 16x16x32
//   s_waitcnt vmcnt(3)           (tile t+1 landed; t+2's 3 stay in flight)
//   s_barrier
// Tail: vmcnt(0) at t=KTILES-2; no sync after last tile.
//
// LDS bank-conflict swizzle (measured 0 conflicts in this exact form):
// row r's 16B chunk q lives at chunk slot q ^ s(r), s(r) = (r>>1)&3.
// Staging lane loads global chunk (tid&3)^((tid>>3)&3); reader xors kq by
// (lr>>1)&3. s(r) invariant under r += multiples of 8.
__global__ __launch_bounds__(512, 4)
void moe_gemm(const __bf16* __restrict__ X,     // [NTOK, DIN] bf16
              const __bf16* __restrict__ W,     // [NEXP, DOUT, DIN] bf16 (B^T form)
              const int* __restrict__ ssi,      // sorted_scattered_idxs [NK]
              const int* __restrict__ offs,     // expert_offsets [NEXP]
              __bf16* __restrict__ flat)        // [NK, DOUT] bf16 out (ungated)
{
  __shared__ char lds[NBUF * SLOT];   // 72 KB ring: per slot A 16 KB | B 8 KB
  __shared__ int  sTok[BM];
  __shared__ int  sF[BM];

  const int tid = threadIdx.x;
  // XCD swizzle: HW assigns XCD = blockIdx % 8; remap so one XCD owns a
  // contiguous chunk of work ids -> same-mtg blocks share an L2. 1152%8==0.
  const int nwg = gridDim.x;
  const int b0  = blockIdx.x;
  const int bid = (b0 & 7) * (nwg >> 3) + (b0 >> 3);
  const int nt  = bid & 15;         // 16 N-tiles of 128
  const int mtg = bid >> 4;         // linear M-tile over all experts

  // Map linear M-tile -> (expert e, tile-in-segment). Uniform scan of 8 offsets.
  int start = 0, end = 0, e, cum = 0, prev = 0, mloc = 0, found = 0;
  for (e = 0; e < NEXP; ++e) {
    int oe  = offs[e];
    int seg = oe - prev;
    int t   = (seg + BM - 1) >> 8;
    if (mtg < cum + t) { start = prev; end = oe; mloc = mtg - cum; found = 1; break; }
    cum += t; prev = oe;
  }
  if (!found) return;  // pad block (uniform exit)

  const int m0 = start + mloc * BM;

  if (tid < BM) {
    int p     = m0 + tid;
    int valid = p < end;
    int f     = ssi[valid ? p : (end - 1)];  // clamp keeps gather in-bounds
    sTok[tid] = f >> 1;                      // token = flat / k (k=2)
    sF[tid]   = valid ? f : -1;
  }
  __syncthreads();   // tables visible; full drain -> clean slate for counted regime

  // Staging: thread tid owns A rows rs = tid>>2 and rs+128, B row rs,
  // swizzled k-chunk kc. LDS dest linear: wave slice base + lane*16.
  const int rs = tid >> 2;                       // 0..127
  const int kc = (tid & 3) ^ ((tid >> 3) & 3);   // swizzled chunk
  const __bf16* pA0 = X + (size_t)sTok[rs]       * DIN + kc * 8;
  const __bf16* pA1 = X + (size_t)sTok[rs + 128] * DIN + kc * 8;
  const __bf16* wBp = W + (size_t)e * DOUT * DIN + (size_t)(nt * BN) * DIN;
  const __bf16* pB0 = wBp + (size_t)rs * DIN + kc * 8;
  char* wsl = (char*)lds + (tid >> 6) * 1024;    // wave-uniform slice base

  // Prologue: stage tiles 0,1 into slots 0,1 (6 loads in flight).
  gl2lds16(pA0, wsl);           gl2lds16(pA1, wsl + 8192);
  gl2lds16(pB0, wsl + 16384);
  pA0 += BK; pA1 += BK; pB0 += BK;
  gl2lds16(pA0, wsl + SLOT);    gl2lds16(pA1, wsl + SLOT + 8192);
  gl2lds16(pB0, wsl + SLOT + 16384);
  pA0 += BK; pA1 += BK; pB0 += BK;   // now at tile-2 source offset

  // Fragment addressing. A frag: lane holds A[m=lr][k=kq*8+j]; LDS row = 64 B.
  const int w   = tid >> 6;
  const int l   = tid & 63;
  const int wm  = w >> 1, wn = w & 1;            // 4 x 2 wave grid
  const int lr  = l & 15;
  const int kq  = l >> 4;
  const int kqs = kq ^ ((lr >> 1) & 3);          // bank-conflict swizzle
  const char* aBase = (const char*)lds + (wm * 64 + lr) * 64 + kqs * 16;
  const char* bBase = (const char*)lds + 16384 + (wn * 64 + lr) * 64 + kqs * 16;

  // Tile 0 arrival: own 3 oldest loads done (tile 1's may stay in flight).
  asm volatile("s_waitcnt vmcnt(3)" ::: "memory");
  __builtin_amdgcn_s_barrier();

  f32x4 acc[4][4] = {};
  int rOff = 0;               // read slot byte offset (t % 3)
  int sOff = 2 * SLOT;        // stage slot byte offset ((t+2) % 3)

  for (int t = 0; t < KTILES; ++t) {
    // Issue next prefetch first (maximizes cover; 3 VMEM issues are cheap).
    if (t < KTILES - 2) {
      char* d = wsl + sOff;
      gl2lds16(pA0, d);  gl2lds16(pA1, d + 8192);  gl2lds16(pB0, d + 16384);
      pA0 += BK; pA1 += BK; pB0 += BK;
      sOff = (sOff == (NBUF - 1) * SLOT) ? 0 : sOff + SLOT;
    }

    const char* aB = aBase + rOff;
    const char* bB = bBase + rOff;
    rOff = (rOff == (NBUF - 1) * SLOT) ? 0 : rOff + SLOT;

    bf16_8 af[4], bf[4];
#pragma unroll
    for (int i = 0; i < 4; ++i) af[i] = *(const bf16_8*)(aB + i * 1024);  // rows i*16
#pragma unroll
    for (int i = 0; i < 4; ++i) bf[i] = *(const bf16_8*)(bB + i * 1024);  // cols i*16

#pragma unroll
    for (int am = 0; am < 4; ++am)
#pragma unroll
      for (int bn = 0; bn < 4; ++bn)
        acc[am][bn] = __builtin_amdgcn_mfma_f32_16x16x32_bf16(
            af[am], bf[bn], acc[am][bn], 0, 0, 0);

    // Arrival of tile t+1 for next iteration; never drain until the tail.
    if (t < KTILES - 2)       { asm volatile("s_waitcnt vmcnt(3)" ::: "memory"); }
    else if (t == KTILES - 2) { asm volatile("s_waitcnt vmcnt(0)" ::: "memory"); }
    if (t < KTILES - 1) __builtin_amdgcn_s_barrier();
  }

  // Epilogue: C/D layout col=lane&15, row=(lane>>4)*4+reg.
  // Plain bf16 stores, ungated; gate applied in combine kernel.
  const int colBase = nt * BN + wn * 64 + lr;
  const int rq = kq * 4;
#pragma unroll
  for (int am = 0; am < 4; ++am) {
#pragma unroll
    for (int v = 0; v < 4; ++v) {
      int rl = wm * 64 + am * 16 + rq + v;
      int f  = sF[rl];
      if (f < 0) continue;
      __bf16* row = flat + (size_t)f * DOUT + colBase;
#pragma unroll
      for (int bn = 0; bn < 4; ++bn)
        row[bn * 16] = (__bf16)acc[am][bn][v];
    }
  }
}

// out[n, :] = g[2n]*flat[2n, :] + g[2n+1]*flat[2n+1, :]
__global__ __launch_bounds__(256)
void combine(const __bf16* __restrict__ flat, const float* __restrict__ gates,
             float* __restrict__ out) {
  const int n = blockIdx.x;
  const int c = threadIdx.x * 8;
  bf16_8 y0 = *(const bf16_8*)(flat + (size_t)(2 * n)     * DOUT + c);
  bf16_8 y1 = *(const bf16_8*)(flat + (size_t)(2 * n + 1) * DOUT + c);
  const float2 g = *(const float2*)(gates + 2 * n);
  float o[8];
#pragma unroll
  for (int j = 0; j < 8; ++j)
    o[j] = g.x * (float)y0[j] + g.y * (float)y1[j];
  float4* dst = (float4*)(out + (size_t)n * DOUT + c);
  dst[0] = *(float4*)&o[0];
  dst[1] = *(float4*)&o[4];
}

extern "C" void kernel_launch(void* const* d_in, const int* in_sizes, int n_in,
                              void* d_out, int out_size, void* d_ws, size_t ws_size,
                              hipStream_t stream) {
  const float* inputs = (const float*)d_in[0];   // [8192, 2048]
  const float* ew     = (const float*)d_in[1];   // [8, 2048, 2048] (E, out, in)
  const float* gates  = (const float*)d_in[2];   // [8192, 2]
  const int*   ssi    = (const int*)d_in[5];     // sorted_scattered_idxs [16384]
  const int*   offs   = (const int*)d_in[6];     // expert_offsets [8]
  float* out = (float*)d_out;

  // ws layout: bf16 W (64 MB) | bf16 X (32 MB) | bf16 flat out (64 MB)
  __bf16* wsW = (__bf16*)d_ws;
  __bf16* wsX = wsW + (size_t)NEXP * DOUT * DIN;
  __bf16* wsF = wsX + (size_t)NTOK * DIN;

  // Dense cvt: one float4 per thread. nW4 = 8 * 2048 * 2048 / 4 = 8388608
  // (multiple of 256 -> uniform per-block branch). Total float4s = 12582912
  // -> 49152 blocks.
  const int nW4 = NEXP * DOUT * DIN / 4;
  const int nX4 = NTOK * DIN / 4;
  cvt_all<<<(nW4 + nX4) / 256, 256, 0, stream>>>(
      (const float4*)ew, (uint2*)wsW, (const float4*)inputs, (uint2*)wsX, nW4);

  // max M-tiles = 64 + 8 (per-expert ceil padding), 16 N-tiles of 128
  moe_gemm<<<72 * 16, 512, 0, stream>>>(wsX, wsW, ssi, offs, wsF);
  combine<<<NTOK, 256, 0, stream>>>(wsF, gates, out);
}